// Round 15
// baseline (6676.082 us; speedup 1.0000x reference)
//
#include <hip/hip_runtime.h>

// FPS: 2 batches x 131072 pts, 4096 samples/batch, seed = point 0.
// EXACT certified lookahead FPS, v10 = r13 (KW=16, PASSED absmax 0)
// with ONE change: SoA LDS mirror (u64 key[] + float x[],y[],z[] + u16
// pool) replacing the stride-5 mirror that caused r13's 3.2e7 bank
// conflicts. No global gathers in the sim (r10/r14's known cost).
// This is the first confound-free test of "does certified depth scale
// with KW": r9 failed on block-tier sim, r13 on bank conflicts, r10/r14
// on per-round global coord gathers.
//
// Per rendezvous round r (all 32 blocks of a batch):
//  1. EXTRACT per wave (exact dists, no barriers): 16 DPP-tournament
//     pops + winner-lane rescan with removal mask. Lanes 2c/2c+1
//     capture pop-c into quads {keylo,keyhi,x,y}/{r,z,0,0}.
//     Key = dist_bits<<32 | r<<17 | (0x1FFFF - idx): u64 order ==
//     (dist desc, idx asc) == jnp.argmax first-index tiebreak.
//  2. SHIP: lanes 0..31 store 16B each (cand C = ws_id*16 + lane/2,
//     quad half = lane&1), sys scope, unacked.
//  3. POLL: wave's 1024-quad quarter, 16 batched loads/lane (ONE vmcnt
//     RT), all-sys; write SoA mirror (even lane: key,x,y; odd: z);
//     barrier.
//  4. CUTOFF = max over 128 wave-slots of 16th-best key (s_key[w*16+15]).
//  5. PRUNE: keys > cutk -> u16 index pool (ballot offsets + 1 LDS
//     atomic/wave; reads cg = i*256+tid, conflict-free). m <= 1920.
//  6. SIM: wave-register tiers NC=8/14/22/30, no barriers, SoA LDS
//     reads only; t=0 always commits (global max = someone's exact
//     top-1 > cutk by uniqueness => in pool); t>=1 iff winner dist
//     STRICTLY > cutoff dist. j >= 1 always.
//  7. COMMIT: rank0 wave0 writes rows S+1..S+j; all blocks min-update
//     register dists per winner, ascending (reference fp order =>
//     bit-exact).
//
// Ring safety (RING=2): a wave ships round r+1 (overwriting slot r-1)
// only after its block's barrier-1 of round r, which requires all 4
// waves' quarter-polls of r, which require ALL 128 wave-slots stored r,
// each after that wave's poll(r-1) finished reading slot r-1. Tags
// embed r; zeroed/stale slots never match (1 <= r <= 4095 < 2^15).

#define NB    32
#define TPB   256
#define PPT   16
#define NPB   131072
#define MSAMP 4096
#define RING  2
#define KW    16                // candidates per wave
#define NWAVE 128               // waves per batch
#define NQUAD (NWAVE * 32)      // 4096 quads per round per batch
#define RB_U32 (NQUAD * 4)      // 16384 u32 = 64KB per ring slot
#define NCAND (NWAVE * KW)      // 2048
#define JCAP  64

typedef unsigned long long u64;
typedef unsigned int u32;
typedef unsigned short u16;
typedef __attribute__((ext_vector_type(4))) u32 u32x4;

__device__ __forceinline__ void st16_sys(u32* p, u32x4 v) {
  asm volatile("global_store_dwordx4 %0, %1, off sc0 sc1"
               :: "v"(p), "v"(v) : "memory");
}
// 16 poll loads issued back-to-back, ONE vmcnt drain (r13-proven).
__device__ __forceinline__ void ld16x16_sys(
    const u32* const* p, u32x4* q) {
  asm volatile(
    "global_load_dwordx4 %0, %16, off sc0 sc1\n\t"
    "global_load_dwordx4 %1, %17, off sc0 sc1\n\t"
    "global_load_dwordx4 %2, %18, off sc0 sc1\n\t"
    "global_load_dwordx4 %3, %19, off sc0 sc1\n\t"
    "global_load_dwordx4 %4, %20, off sc0 sc1\n\t"
    "global_load_dwordx4 %5, %21, off sc0 sc1\n\t"
    "global_load_dwordx4 %6, %22, off sc0 sc1\n\t"
    "global_load_dwordx4 %7, %23, off sc0 sc1\n\t"
    "global_load_dwordx4 %8, %24, off sc0 sc1\n\t"
    "global_load_dwordx4 %9, %25, off sc0 sc1\n\t"
    "global_load_dwordx4 %10, %26, off sc0 sc1\n\t"
    "global_load_dwordx4 %11, %27, off sc0 sc1\n\t"
    "global_load_dwordx4 %12, %28, off sc0 sc1\n\t"
    "global_load_dwordx4 %13, %29, off sc0 sc1\n\t"
    "global_load_dwordx4 %14, %30, off sc0 sc1\n\t"
    "global_load_dwordx4 %15, %31, off sc0 sc1\n\t"
    "s_waitcnt vmcnt(0)"
    : "=v"(q[0]), "=v"(q[1]), "=v"(q[2]), "=v"(q[3]),
      "=v"(q[4]), "=v"(q[5]), "=v"(q[6]), "=v"(q[7]),
      "=v"(q[8]), "=v"(q[9]), "=v"(q[10]), "=v"(q[11]),
      "=v"(q[12]), "=v"(q[13]), "=v"(q[14]), "=v"(q[15])
    : "v"(p[0]), "v"(p[1]), "v"(p[2]), "v"(p[3]),
      "v"(p[4]), "v"(p[5]), "v"(p[6]), "v"(p[7]),
      "v"(p[8]), "v"(p[9]), "v"(p[10]), "v"(p[11]),
      "v"(p[12]), "v"(p[13]), "v"(p[14]), "v"(p[15])
    : "memory");
}

// ---- DPP helpers (proven r2-r14) ---------------------------------------
template<int CTRL>
__device__ __forceinline__ u64 dpp_move64(u64 x) {
  int lo = (int)(u32)(x & 0xFFFFFFFFull);
  int hi = (int)(u32)(x >> 32);
  int nlo = __builtin_amdgcn_update_dpp(lo, lo, CTRL, 0xF, 0xF, false);
  int nhi = __builtin_amdgcn_update_dpp(hi, hi, CTRL, 0xF, 0xF, false);
  return ((u64)(u32)nhi << 32) | (u64)(u32)nlo;
}
#define DPP_ROW_SHR(n)  (0x110 + (n))
#define DPP_BCAST15     0x142
#define DPP_BCAST31     0x143

__device__ __forceinline__ u64 dpp_max64_to63(u64 k) {
  u64 t;
  t = dpp_move64<DPP_ROW_SHR(1)>(k); if (t > k) k = t;
  t = dpp_move64<DPP_ROW_SHR(2)>(k); if (t > k) k = t;
  t = dpp_move64<DPP_ROW_SHR(4)>(k); if (t > k) k = t;
  t = dpp_move64<DPP_ROW_SHR(8)>(k); if (t > k) k = t;
  t = dpp_move64<DPP_BCAST15>(k);    if (t > k) k = t;
  t = dpp_move64<DPP_BCAST31>(k);    if (t > k) k = t;
  return k;                                   // lane63 = wave max
}
__device__ __forceinline__ u64 bcast_key(u64 k, int srclane) {
  u32 lo = (u32)__builtin_amdgcn_readlane((int)(u32)(k & 0xFFFFFFFFull), srclane);
  u32 hi = (u32)__builtin_amdgcn_readlane((int)(u32)(k >> 32), srclane);
  return ((u64)hi << 32) | (u64)lo;
}
__device__ __forceinline__ float bcast_f32(float v, int srclane) {
  return __uint_as_float((u32)__builtin_amdgcn_readlane((int)__float_as_uint(v), srclane));
}

// ---- pruned in-register sim, NO barriers, SoA LDS reads only ----------
// (r13 sim verbatim except init reads the SoA mirror)
template<int NC>
__device__ __forceinline__ int sim_wave(const u64* s_key, const float* s_x,
    const float* s_y, const float* s_z, const u16* s_pidx,
    int m, u32 cutd, int jmax, int lane, float& ox, float& oy, float& oz) {
#pragma clang fp contract(off)
  u64 ck[NC]; float cx[NC], cy[NC], cz[NC];
#pragma unroll
  for (int i = 0; i < NC; ++i) {
    int idx = lane + i * 64;
    if (idx < m) {
      int p = (int)s_pidx[idx];
      ck[i] = s_key[p];
      cx[i] = s_x[p]; cy[i] = s_y[p]; cz[i] = s_z[p];
    } else { ck[i] = 0; cx[i] = cy[i] = cz[i] = 0.f; }
  }
  int j = 0;
  for (int t = 0; t < jmax; ++t) {
    u64 tk = ck[0]; float mx = cx[0], my = cy[0], mz = cz[0];
#pragma unroll
    for (int i = 1; i < NC; ++i)
      if (ck[i] > tk) { tk = ck[i]; mx = cx[i]; my = cy[i]; mz = cz[i]; }
    u64 wk = bcast_key(dpp_max64_to63(tk), 63);
    if (t > 0 && (u32)(wk >> 32) <= cutd) break;   // not certified: stop
    int wl = __ffsll(__ballot(tk == wk)) - 1;
    float wx = bcast_f32(mx, wl), wy = bcast_f32(my, wl), wz = bcast_f32(mz, wl);
    if (lane == t) { ox = wx; oy = wy; oz = wz; }  // stash winner t
    j = t + 1;
#pragma unroll
    for (int i = 0; i < NC; ++i) {
      float dx = cx[i]-wx, dy = cy[i]-wy, dz = cz[i]-wz;
      float d2 = __fadd_rn(__fadd_rn(__fmul_rn(dx,dx), __fmul_rn(dy,dy)),
                           __fmul_rn(dz,dz));
      float nd = fminf(__uint_as_float((u32)(ck[i] >> 32)), d2);
      ck[i] = ((u64)__float_as_uint(nd) << 32) | (ck[i] & 0xFFFFFFFFull);
    }
  }
  return j;
}

__global__ __launch_bounds__(TPB, 1)
void fps_kernel(const float4* __restrict__ pts, float* __restrict__ out,
                u32* __restrict__ slots)
{
#pragma clang fp contract(off)
  const int batch = blockIdx.x >> 5;
  const int rank  = blockIdx.x & (NB - 1);
  const int tid   = threadIdx.x;
  const int lane  = tid & 63;
  const int wv    = tid >> 6;
  const int ws_id = rank * 4 + wv;           // wave-slot 0..127

  __shared__ __attribute__((aligned(16))) u64 s_key[NCAND];  // 16 KB
  __shared__ float s_x[NCAND], s_y[NCAND], s_z[NCAND];       // 24 KB
  __shared__ u16   s_pidx[NCAND];            // 4 KB index pool
  __shared__ int   s_cnt2[2];                // ping-pong compact counters

  const float4* bpts = pts + (size_t)batch * NPB;
  u32* bslots = slots + (size_t)batch * (RING * RB_U32);
  const int base = rank * (TPB * PPT);

  float px[PPT], py[PPT], pz[PPT], dist[PPT];
  float4 seed = bpts[0];
  const float sx = seed.y, sy = seed.z, sz = seed.w;
#pragma unroll
  for (int k = 0; k < PPT; ++k) {
    float4 p = bpts[base + k * TPB + tid];   // row = (b, x, y, z)
    px[k] = p.y; py[k] = p.z; pz[k] = p.w;
    float dx = px[k]-sx, dy = py[k]-sy, dz = pz[k]-sz;
    dist[k] = __fadd_rn(__fadd_rn(__fmul_rn(dx,dx), __fmul_rn(dy,dy)),
                        __fmul_rn(dz,dz));   // == reference dist init
  }
  if (rank == 0 && tid == 0) {
    float4 o; o.x=(float)batch; o.y=sx; o.z=sy; o.w=sz;
    *(float4*)(out + (size_t)batch * MSAMP * 4) = o;
  }
  if (tid == 0) { s_cnt2[0] = 0; s_cnt2[1] = 0; }
  __syncthreads();

  int S = 0; u32 r = 0;
  float ox = 0.f, oy = 0.f, oz = 0.f;

  while (S < MSAMP - 1) {
    r += 1;
    const int rem = (MSAMP - 1) - S;
    const int jmax = (rem < JCAP) ? rem : JCAP;

    // ---- EXTRACT: wave top-16, pure DPP, no barriers (r13 verbatim) ----
    u32 mask = 0; u64 tk = 0; float tx=0.f, ty=0.f, tz=0.f; int tbk = 0;
#pragma unroll
    for (int k = 0; k < PPT; ++k) {
      u64 kk = ((u64)__float_as_uint(dist[k]) << 32) | ((u64)r << 17) |
               (u64)(0x1FFFF - (base + k * TPB + tid));
      if (kk > tk) { tk = kk; tx = px[k]; ty = py[k]; tz = pz[k]; tbk = k; }
    }
    u32x4 shipq;
    for (int c = 0; c < KW; ++c) {
      u64 wk = bcast_key(dpp_max64_to63(tk), 63);
      int wl = __ffsll(__ballot(tk == wk)) - 1;
      float wx = bcast_f32(tx, wl), wy = bcast_f32(ty, wl), wz = bcast_f32(tz, wl);
      if (lane == 2*c)     { shipq.x=(u32)(wk & 0xFFFFFFFFull); shipq.y=(u32)(wk>>32);
                             shipq.z=__float_as_uint(wx); shipq.w=__float_as_uint(wy); }
      if (lane == 2*c + 1) { shipq.x=r; shipq.y=__float_as_uint(wz);
                             shipq.z=0u; shipq.w=0u; }
      if (tk == wk) {                        // my point won: mask + rescan
        mask |= 1u << tbk;
        tk = 0; tx = ty = tz = 0.f; tbk = 0;
#pragma unroll
        for (int k = 0; k < PPT; ++k) {
          if (!((mask >> k) & 1u)) {
            u64 kk = ((u64)__float_as_uint(dist[k]) << 32) | ((u64)r << 17) |
                     (u64)(0x1FFFF - (base + k * TPB + tid));
            if (kk > tk) { tk = kk; tx = px[k]; ty = py[k]; tz = pz[k]; tbk = k; }
          }
        }
      }
    }

    // ---- SHIP: lanes 0..31 store 16B each (r13 verbatim) ----
    u32* ring = bslots + (size_t)(r & (RING - 1)) * RB_U32;
    if (lane < 32)
      st16_sys(ring + ((ws_id * 16 + (lane >> 1)) * 8 + (lane & 1) * 4), shipq);

    // ---- POLL: my wave's 1024-quad quarter, 16 loads/lane (r13) ----
    const int gb = wv * 1024 + lane;
    const u32* pp[16]; u32x4 q[16];
#pragma unroll
    for (int i = 0; i < 16; ++i) pp[i] = ring + (size_t)(gb + 64 * i) * 4;
    for (;;) {
      ld16x16_sys(pp, q);
      bool ok;
      if ((lane & 1) == 0) {
        ok = true;
#pragma unroll
        for (int i = 0; i < 16; ++i) ok = ok && ((q[i].x >> 17) == r);
      } else {
        ok = true;
#pragma unroll
        for (int i = 0; i < 16; ++i) ok = ok && (q[i].x == r);
      }
      if (__ballot(ok) == ~0ull) break;
      __builtin_amdgcn_s_sleep(1);
    }
    // reset NEXT round's compact counter (safe: ordered by mirror barriers)
    if (tid == 0) s_cnt2[(r + 1) & 1] = 0;
    // SoA mirror: even lane writes key/x/y at C, odd lane writes z at C
    {
#pragma unroll
      for (int i = 0; i < 16; ++i) {
        int C = (gb + 64 * i) >> 1;          // cand index, pair-shared
        if ((lane & 1) == 0) {
          s_key[C] = ((u64)q[i].y << 32) | (u64)q[i].x;
          s_x[C] = __uint_as_float(q[i].z);
          s_y[C] = __uint_as_float(q[i].w);
        } else {
          s_z[C] = __uint_as_float(q[i].y);
        }
      }
    }
    __syncthreads();                         // barrier 1: mirror complete

    // ---- CUTOFF: max over 128 wave-16th keys (per wave, no barrier) ----
    u64 cutk;
    {
      u64 k0 = s_key[lane * 16 + 15];
      u64 k1 = s_key[(lane + 64) * 16 + 15];
      u64 ct = (k0 > k1) ? k0 : k1;
      cutk = bcast_key(dpp_max64_to63(ct), 63);
    }
    const u32 cutd = (u32)(cutk >> 32);

    // ---- PRUNE: wave-aggregated u16 append (conflict-free reads) ----
    int* cnt = &s_cnt2[r & 1];
    bool hh[8]; int myoff[8]; int tot = 0;
    const u64 ltmask = (1ull << lane) - 1ull;
#pragma unroll
    for (int i = 0; i < 8; ++i) {
      int cg = i * 256 + tid;                // lanes consecutive: no conflict
      u64 kk = s_key[cg];
      hh[i] = kk > cutk;
      u64 b = __ballot(hh[i]);
      myoff[i] = tot + __popcll(b & ltmask);
      tot += __popcll(b);
    }
    int pbase = 0;
    if (lane == 0) pbase = atomicAdd(cnt, tot);
    pbase = __builtin_amdgcn_readfirstlane(pbase);
#pragma unroll
    for (int i = 0; i < 8; ++i)
      if (hh[i]) s_pidx[pbase + myoff[i]] = (u16)(i * 256 + tid);
    __syncthreads();                         // barrier 2: pool + m final
    const int m = *cnt;                      // m <= 128*15 = 1920 (proven)

    // ---- SIM: wave-register tiers (NC=30 covers 1920) ----
    int j;
    if      (m <= 512)  j = sim_wave<8> (s_key, s_x, s_y, s_z, s_pidx, m, cutd, jmax, lane, ox, oy, oz);
    else if (m <= 896)  j = sim_wave<14>(s_key, s_x, s_y, s_z, s_pidx, m, cutd, jmax, lane, ox, oy, oz);
    else if (m <= 1408) j = sim_wave<22>(s_key, s_x, s_y, s_z, s_pidx, m, cutd, jmax, lane, ox, oy, oz);
    else                j = sim_wave<30>(s_key, s_x, s_y, s_z, s_pidx, m, cutd, jmax, lane, ox, oy, oz);

    // ---- COMMIT: output rows + batched register dist update ----
    if (rank == 0 && wv == 0 && lane < j) {
      float4 o; o.x = (float)batch; o.y = ox; o.z = oy; o.w = oz;
      *(float4*)(out + (size_t)(batch * MSAMP + S + 1 + lane) * 4) = o;
    }
    for (int i = 0; i < j; ++i) {            // ascending = reference order
      float wx = bcast_f32(ox, i), wy = bcast_f32(oy, i), wz = bcast_f32(oz, i);
#pragma unroll
      for (int k = 0; k < PPT; ++k) {
        float dx = px[k]-wx, dy = py[k]-wy, dz = pz[k]-wz;
        float d2 = __fadd_rn(__fadd_rn(__fmul_rn(dx,dx), __fmul_rn(dy,dy)),
                             __fmul_rn(dz,dz));
        dist[k] = fminf(dist[k], d2);
      }
    }
    S += j;
  }
}

extern "C" void kernel_launch(void* const* d_in, const int* in_sizes, int n_in,
                              void* d_out, int out_size, void* d_ws, size_t ws_size,
                              hipStream_t stream) {
  const float4* pts = (const float4*)d_in[0];
  float* out = (float*)d_out;
  u32* slots = (u32*)d_ws;

  // Zero both batches' rings (256 KB): stale tags can never validate.
  hipMemsetAsync(d_ws, 0, (size_t)2 * RING * RB_U32 * 4, stream);

  dim3 grid(2 * NB), block(TPB);
  hipLaunchKernelGGL(fps_kernel, grid, block, 0, stream, pts, out, slots);
}

// Round 16
// 3696.986 us; speedup vs baseline: 1.8058x; 1.8058x over previous
//
#include <hip/hip_runtime.h>

// FPS: 2 batches x 131072 pts, 4096 samples/batch, seed = point 0.
// EXACT certified lookahead FPS, v11 = r12 (3613us, PASSED, best) with a
// FLAG-GATED rendezvous. r15's counters: ~22MB of sc1 poll traffic per
// round per batch (~20+ full 1MB sweeps) => the rendezvous is fabric-
// CONGESTION-bound: the poll storm delays store visibility which extends
// the spin. Fix: after each wave ships its 16 quads, ack them
// (s_waitcnt vmcnt(0) => data reached the coherence point), barrier,
// tid0 stores a per-block done-flag (value=r). Pollers pre-spin on the
// 32 FLAGS only (128B/sweep, ~8000x less traffic), then run r12's
// tagged data poll UNCHANGED (expected 1 iteration). Flags are a pure
// throttle: correctness rests on the proven tagged-retry loop, and
// ack-before-flag guarantees data visibility once flags match anyway.
// KW=16 depth lever is CLOSED (r9/r13/r15 all ~6-6.7ms: j does not
// scale with KW; FPS winner-suppression pins j~8).
//
// Everything below the sync layer is r12 VERBATIM: KW=8 extraction with
// winner rescans, 32B candidates (coords on the wire), batched 8-load
// tagged poll, LDS mirror (68-u32 padded), per-wave DPP cutoff,
// wave-aggregated prune, register-tier sim (NC<=14, m<=896 proven),
// dist-cert sim (t=0 always commits; t>=1 iff dist > cutd), commit +
// ascending bit-exact dist update.
// Key = dist_bits<<32 | r<<17 | (0x1FFFF - idx): u64 order ==
// (dist desc, idx asc) == jnp.argmax first-index tiebreak.
//
// Ring safety (RING=2, r12's induction unchanged - flags only delay):
// a wave ships round r+1 (overwriting slot r-1) only after its block's
// barrier-1 of round r, which requires all 4 waves' tagged polls of r,
// which require ALL 128 wave-slots stored r, each after that wave's
// poll(r-1) finished reading slot r-1. Flag slot (r&1) reuse: block A
// stores flag(r+1) only after A passed poll(r), which requires every
// block's ship(r), which happens after that block finished reading
// flags(r-1). Tags embed r; zeroed/stale never match (1<=r<=4095<2^15).

#define NB    32
#define TPB   256
#define PPT   16
#define NPB   131072
#define MSAMP 4096
#define RING  2
#define KW    8                 // candidates per wave
#define NWAVE 128               // waves per batch
#define NQUAD (NWAVE * 16)      // 2048 quads per round per batch
#define RB_U32 (NQUAD * 4)      // 8192 u32 = 32KB per ring slot
#define NCAND (NWAVE * KW)      // 1024
#define JCAP  64

typedef unsigned long long u64;
typedef unsigned int u32;
typedef __attribute__((ext_vector_type(4))) u32 u32x4;

__device__ __forceinline__ void st16_sys(u32* p, u32x4 v) {
  asm volatile("global_store_dwordx4 %0, %1, off sc0 sc1"
               :: "v"(p), "v"(v) : "memory");
}
__device__ __forceinline__ void st32_sys(u32* p, u32 v) {
  asm volatile("global_store_dword %0, %1, off sc0 sc1"
               :: "v"(p), "v"(v) : "memory");
}
__device__ __forceinline__ u32 ld32_sys(const u32* p) {
  u32 r;
  asm volatile("global_load_dword %0, %1, off sc0 sc1\n\t"
               "s_waitcnt vmcnt(0)" : "=v"(r) : "v"(p) : "memory");
  return r;
}
// 8 poll loads issued back-to-back, ONE vmcnt drain (single RT).
__device__ __forceinline__ void ld16x8_sys(
    const u32* p0, const u32* p1, const u32* p2, const u32* p3,
    const u32* p4, const u32* p5, const u32* p6, const u32* p7,
    u32x4& q0, u32x4& q1, u32x4& q2, u32x4& q3,
    u32x4& q4, u32x4& q5, u32x4& q6, u32x4& q7) {
  asm volatile(
    "global_load_dwordx4 %0, %8, off sc0 sc1\n\t"
    "global_load_dwordx4 %1, %9, off sc0 sc1\n\t"
    "global_load_dwordx4 %2, %10, off sc0 sc1\n\t"
    "global_load_dwordx4 %3, %11, off sc0 sc1\n\t"
    "global_load_dwordx4 %4, %12, off sc0 sc1\n\t"
    "global_load_dwordx4 %5, %13, off sc0 sc1\n\t"
    "global_load_dwordx4 %6, %14, off sc0 sc1\n\t"
    "global_load_dwordx4 %7, %15, off sc0 sc1\n\t"
    "s_waitcnt vmcnt(0)"
    : "=v"(q0), "=v"(q1), "=v"(q2), "=v"(q3),
      "=v"(q4), "=v"(q5), "=v"(q6), "=v"(q7)
    : "v"(p0), "v"(p1), "v"(p2), "v"(p3),
      "v"(p4), "v"(p5), "v"(p6), "v"(p7)
    : "memory");
}

// ---- DPP helpers (proven r2-r15) ---------------------------------------
template<int CTRL>
__device__ __forceinline__ u64 dpp_move64(u64 x) {
  int lo = (int)(u32)(x & 0xFFFFFFFFull);
  int hi = (int)(u32)(x >> 32);
  int nlo = __builtin_amdgcn_update_dpp(lo, lo, CTRL, 0xF, 0xF, false);
  int nhi = __builtin_amdgcn_update_dpp(hi, hi, CTRL, 0xF, 0xF, false);
  return ((u64)(u32)nhi << 32) | (u64)(u32)nlo;
}
#define DPP_ROW_SHR(n)  (0x110 + (n))
#define DPP_BCAST15     0x142
#define DPP_BCAST31     0x143

__device__ __forceinline__ u64 dpp_max64_to63(u64 k) {
  u64 t;
  t = dpp_move64<DPP_ROW_SHR(1)>(k); if (t > k) k = t;
  t = dpp_move64<DPP_ROW_SHR(2)>(k); if (t > k) k = t;
  t = dpp_move64<DPP_ROW_SHR(4)>(k); if (t > k) k = t;
  t = dpp_move64<DPP_ROW_SHR(8)>(k); if (t > k) k = t;
  t = dpp_move64<DPP_BCAST15>(k);    if (t > k) k = t;
  t = dpp_move64<DPP_BCAST31>(k);    if (t > k) k = t;
  return k;                                   // lane63 = wave max
}
__device__ __forceinline__ u64 bcast_key(u64 k, int srclane) {
  u32 lo = (u32)__builtin_amdgcn_readlane((int)(u32)(k & 0xFFFFFFFFull), srclane);
  u32 hi = (u32)__builtin_amdgcn_readlane((int)(u32)(k >> 32), srclane);
  return ((u64)hi << 32) | (u64)lo;
}
__device__ __forceinline__ float bcast_f32(float v, int srclane) {
  return __uint_as_float((u32)__builtin_amdgcn_readlane((int)__float_as_uint(v), srclane));
}

// ---- pruned in-register sim, NO barriers, identical on all waves ------
// (r12 verbatim; cert: t=0 always commits, t>=1 needs dist > cutd)
template<int NC>
__device__ __forceinline__ int sim_wave(const u32* s_pool, int m, u32 cutd,
    int jmax, int lane, float& ox, float& oy, float& oz) {
#pragma clang fp contract(off)
  u64 ck[NC]; float cx[NC], cy[NC], cz[NC];
#pragma unroll
  for (int i = 0; i < NC; ++i) {
    int idx = lane + i * 64;
    if (idx < m) {
      const u32* b = s_pool + idx * 5;
      ck[i] = ((u64)b[1] << 32) | (u64)b[0];
      cx[i] = __uint_as_float(b[2]); cy[i] = __uint_as_float(b[3]);
      cz[i] = __uint_as_float(b[4]);
    } else { ck[i] = 0; cx[i] = cy[i] = cz[i] = 0.f; }
  }
  int j = 0;
  for (int t = 0; t < jmax; ++t) {
    u64 tk = ck[0]; float mx = cx[0], my = cy[0], mz = cz[0];
#pragma unroll
    for (int i = 1; i < NC; ++i)
      if (ck[i] > tk) { tk = ck[i]; mx = cx[i]; my = cy[i]; mz = cz[i]; }
    u64 wk = bcast_key(dpp_max64_to63(tk), 63);
    if (t > 0 && (u32)(wk >> 32) <= cutd) break;   // not certified: stop
    int wl = __ffsll(__ballot(tk == wk)) - 1;
    float wx = bcast_f32(mx, wl), wy = bcast_f32(my, wl), wz = bcast_f32(mz, wl);
    if (lane == t) { ox = wx; oy = wy; oz = wz; }  // stash winner t
    j = t + 1;
#pragma unroll
    for (int i = 0; i < NC; ++i) {
      float dx = cx[i]-wx, dy = cy[i]-wy, dz = cz[i]-wz;
      float d2 = __fadd_rn(__fadd_rn(__fmul_rn(dx,dx), __fmul_rn(dy,dy)),
                           __fmul_rn(dz,dz));
      float nd = fminf(__uint_as_float((u32)(ck[i] >> 32)), d2);
      ck[i] = ((u64)__float_as_uint(nd) << 32) | (ck[i] & 0xFFFFFFFFull);
    }
  }
  return j;
}

__global__ __launch_bounds__(TPB, 1)
void fps_kernel(const float4* __restrict__ pts, float* __restrict__ out,
                u32* __restrict__ slots)
{
#pragma clang fp contract(off)
  const int batch = blockIdx.x >> 5;
  const int rank  = blockIdx.x & (NB - 1);
  const int tid   = threadIdx.x;
  const int lane  = tid & 63;
  const int wv    = tid >> 6;
  const int ws_id = rank * 4 + wv;           // wave-slot 0..127

  __shared__ u32   s_quads[NWAVE * 68];      // mirror, 68-u32 padded slots
  __shared__ u32   s_pool[NCAND * 5];        // pruned candidates
  __shared__ int   s_cnt2[2];                // ping-pong compact counters

  const float4* bpts = pts + (size_t)batch * NPB;
  u32* bslots = slots + (size_t)batch * (RING * RB_U32);
  u32* bflags = slots + 2 * RING * RB_U32 + batch * (RING * NB);
  const int base = rank * (TPB * PPT);

  float px[PPT], py[PPT], pz[PPT], dist[PPT];
  float4 seed = bpts[0];
  const float sx = seed.y, sy = seed.z, sz = seed.w;
#pragma unroll
  for (int k = 0; k < PPT; ++k) {
    float4 p = bpts[base + k * TPB + tid];   // row = (b, x, y, z)
    px[k] = p.y; py[k] = p.z; pz[k] = p.w;
    float dx = px[k]-sx, dy = py[k]-sy, dz = pz[k]-sz;
    dist[k] = __fadd_rn(__fadd_rn(__fmul_rn(dx,dx), __fmul_rn(dy,dy)),
                        __fmul_rn(dz,dz));   // == reference dist init
  }
  if (rank == 0 && tid == 0) {
    float4 o; o.x=(float)batch; o.y=sx; o.z=sy; o.w=sz;
    *(float4*)(out + (size_t)batch * MSAMP * 4) = o;
  }
  if (tid == 0) { s_cnt2[0] = 0; s_cnt2[1] = 0; }
  __syncthreads();

  int S = 0; u32 r = 0;
  float ox = 0.f, oy = 0.f, oz = 0.f;

  while (S < MSAMP - 1) {
    r += 1;
    const int rem = (MSAMP - 1) - S;
    const int jmax = (rem < JCAP) ? rem : JCAP;

    // ---- EXTRACT: wave top-8, pure DPP, no barriers (r12 verbatim) ----
    u32 mask = 0; u64 tk = 0; float tx=0.f, ty=0.f, tz=0.f; int tbk = 0;
#pragma unroll
    for (int k = 0; k < PPT; ++k) {
      u64 kk = ((u64)__float_as_uint(dist[k]) << 32) | ((u64)r << 17) |
               (u64)(0x1FFFF - (base + k * TPB + tid));
      if (kk > tk) { tk = kk; tx = px[k]; ty = py[k]; tz = pz[k]; tbk = k; }
    }
    u32x4 shipq;
    for (int c = 0; c < KW; ++c) {
      u64 wk = bcast_key(dpp_max64_to63(tk), 63);
      int wl = __ffsll(__ballot(tk == wk)) - 1;
      float wx = bcast_f32(tx, wl), wy = bcast_f32(ty, wl), wz = bcast_f32(tz, wl);
      if (lane == 2*c)     { shipq.x=(u32)(wk & 0xFFFFFFFFull); shipq.y=(u32)(wk>>32);
                             shipq.z=__float_as_uint(wx); shipq.w=__float_as_uint(wy); }
      if (lane == 2*c + 1) { shipq.x=r; shipq.y=__float_as_uint(wz);
                             shipq.z=0u; shipq.w=0u; }
      if (tk == wk) {                        // my point won: mask + rescan
        mask |= 1u << tbk;
        tk = 0; tx = ty = tz = 0.f; tbk = 0;
#pragma unroll
        for (int k = 0; k < PPT; ++k) {
          if (!((mask >> k) & 1u)) {
            u64 kk = ((u64)__float_as_uint(dist[k]) << 32) | ((u64)r << 17) |
                     (u64)(0x1FFFF - (base + k * TPB + tid));
            if (kk > tk) { tk = kk; tx = px[k]; ty = py[k]; tz = pz[k]; tbk = k; }
          }
        }
      }
    }

    // ---- SHIP: wave stores its 16 quads, then ACK (coherence point) ----
    u32* ring = bslots + (size_t)(r & (RING - 1)) * RB_U32;
    if (lane < 16) st16_sys(ring + (ws_id * 16 + lane) * 4, shipq);
    asm volatile("s_waitcnt vmcnt(0)" ::: "memory");   // data globally visible
    __syncthreads();                         // all 4 waves shipped+acked
    u32* flags = bflags + (size_t)(r & 1) * NB;
    if (tid == 0) st32_sys(flags + rank, r); // block-done flag (after acks)

    // ---- FLAG PRE-SPIN: 32 x 4B per sweep (throttle; not correctness) ----
    for (;;) {
      u32 f = (lane < NB) ? ld32_sys(flags + lane) : r;
      if (__ballot(f == r) == ~0ull) break;
      __builtin_amdgcn_s_sleep(2);
    }

    // ---- POLL (r12 verbatim, expected 1 iteration now) ----
    const int gb = wv * 512 + lane;
    const u32 *pp0 = ring + (gb      ) * 4, *pp1 = ring + (gb +  64) * 4,
              *pp2 = ring + (gb + 128) * 4, *pp3 = ring + (gb + 192) * 4,
              *pp4 = ring + (gb + 256) * 4, *pp5 = ring + (gb + 320) * 4,
              *pp6 = ring + (gb + 384) * 4, *pp7 = ring + (gb + 448) * 4;
    u32x4 q0,q1,q2,q3,q4,q5,q6,q7;
    for (u32 it = 0; ; ++it) {
      ld16x8_sys(pp0,pp1,pp2,pp3,pp4,pp5,pp6,pp7, q0,q1,q2,q3,q4,q5,q6,q7);
      bool ok;
      if ((lane & 1) == 0)
        ok = ((q0.x>>17)==r)&&((q1.x>>17)==r)&&((q2.x>>17)==r)&&((q3.x>>17)==r)&&
             ((q4.x>>17)==r)&&((q5.x>>17)==r)&&((q6.x>>17)==r)&&((q7.x>>17)==r);
      else
        ok = (q0.x==r)&&(q1.x==r)&&(q2.x==r)&&(q3.x==r)&&
             (q4.x==r)&&(q5.x==r)&&(q6.x==r)&&(q7.x==r);
      if (__ballot(ok) == ~0ull) break;
      __builtin_amdgcn_s_sleep(1);
    }
    // reset NEXT round's compact counter (safe: ordered by mirror barriers)
    if (tid == 0) s_cnt2[(r + 1) & 1] = 0;
    // mirror my 8 quads to LDS (padded slots: 68 u32 / wave-slot)
    {
      int g = gb;
      *(u32x4*)&s_quads[(g>>4)*68 + (g&15)*4] = q0; g += 64;
      *(u32x4*)&s_quads[(g>>4)*68 + (g&15)*4] = q1; g += 64;
      *(u32x4*)&s_quads[(g>>4)*68 + (g&15)*4] = q2; g += 64;
      *(u32x4*)&s_quads[(g>>4)*68 + (g&15)*4] = q3; g += 64;
      *(u32x4*)&s_quads[(g>>4)*68 + (g&15)*4] = q4; g += 64;
      *(u32x4*)&s_quads[(g>>4)*68 + (g&15)*4] = q5; g += 64;
      *(u32x4*)&s_quads[(g>>4)*68 + (g&15)*4] = q6; g += 64;
      *(u32x4*)&s_quads[(g>>4)*68 + (g&15)*4] = q7;
    }
    __syncthreads();                         // barrier 1: all 2048 in LDS

    // ---- CUTOFF: max over 128 wave-8th keys (per wave, no barrier) ----
    u64 cutk;
    {
      int w0 = lane, w1 = lane + 64;
      u64 k0 = ((u64)s_quads[w0*68 + 57] << 32) | (u64)s_quads[w0*68 + 56];
      u64 k1 = ((u64)s_quads[w1*68 + 57] << 32) | (u64)s_quads[w1*68 + 56];
      u64 ct = (k0 > k1) ? k0 : k1;
      cutk = bcast_key(dpp_max64_to63(ct), 63);
    }
    const u32 cutd = (u32)(cutk >> 32);

    // ---- PRUNE: wave-aggregated (ballot offsets + 1 atomic/wave) ----
    int* cnt = &s_cnt2[r & 1];
    bool hh[4]; int myoff[4]; int tot = 0;
    u32 clo[4], chi[4], cx4[4], cy4[4], cz4[4];
    const u64 ltmask = (1ull << lane) - 1ull;
#pragma unroll
    for (int i = 0; i < 4; ++i) {
      int cg = tid * 4 + i;
      int qb = (cg >> 3) * 68 + (cg & 7) * 8;
      u32 lo = s_quads[qb], hi = s_quads[qb + 1];
      u64 kk = ((u64)hi << 32) | (u64)lo;
      clo[i] = lo; chi[i] = hi;
      cx4[i] = s_quads[qb+2]; cy4[i] = s_quads[qb+3]; cz4[i] = s_quads[qb+5];
      hh[i] = kk > cutk;
      u64 b = __ballot(hh[i]);
      myoff[i] = tot + __popcll(b & ltmask);
      tot += __popcll(b);
    }
    int pbase = 0;
    if (lane == 0) pbase = atomicAdd(cnt, tot);
    pbase = __builtin_amdgcn_readfirstlane(pbase);
#pragma unroll
    for (int i = 0; i < 4; ++i)
      if (hh[i]) {
        u32* d = &s_pool[(pbase + myoff[i]) * 5];
        d[0]=clo[i]; d[1]=chi[i]; d[2]=cx4[i]; d[3]=cy4[i]; d[4]=cz4[i];
      }
    __syncthreads();                         // barrier 2: pool + m final
    const int m = *cnt;                      // m <= 128*7 = 896 (proven)

    // ---- SIM: wave-register tiers only (NC=14 covers 896) ----
    int j;
    if      (m <=  64) j = sim_wave<1>(s_pool, m, cutd, jmax, lane, ox, oy, oz);
    else if (m <= 128) j = sim_wave<2>(s_pool, m, cutd, jmax, lane, ox, oy, oz);
    else if (m <= 256) j = sim_wave<4>(s_pool, m, cutd, jmax, lane, ox, oy, oz);
    else if (m <= 512) j = sim_wave<8>(s_pool, m, cutd, jmax, lane, ox, oy, oz);
    else               j = sim_wave<14>(s_pool, m, cutd, jmax, lane, ox, oy, oz);

    // ---- COMMIT: output rows + batched register dist update ----
    if (rank == 0 && wv == 0 && lane < j) {
      float4 o; o.x = (float)batch; o.y = ox; o.z = oy; o.w = oz;
      *(float4*)(out + (size_t)(batch * MSAMP + S + 1 + lane) * 4) = o;
    }
    for (int i = 0; i < j; ++i) {            // ascending = reference order
      float wx = bcast_f32(ox, i), wy = bcast_f32(oy, i), wz = bcast_f32(oz, i);
#pragma unroll
      for (int k = 0; k < PPT; ++k) {
        float dx = px[k]-wx, dy = py[k]-wy, dz = pz[k]-wz;
        float d2 = __fadd_rn(__fadd_rn(__fmul_rn(dx,dx), __fmul_rn(dy,dy)),
                             __fmul_rn(dz,dz));
        dist[k] = fminf(dist[k], d2);
      }
    }
    S += j;
  }
}

extern "C" void kernel_launch(void* const* d_in, const int* in_sizes, int n_in,
                              void* d_out, int out_size, void* d_ws, size_t ws_size,
                              hipStream_t stream) {
  const float4* pts = (const float4*)d_in[0];
  float* out = (float*)d_out;
  u32* slots = (u32*)d_ws;

  // Zero both batches' rings (128 KB) + flags (512 B): stale tags/flags
  // can never validate.
  hipMemsetAsync(d_ws, 0,
                 (size_t)2 * RING * RB_U32 * 4 + (size_t)2 * RING * NB * 4,
                 stream);

  dim3 grid(2 * NB), block(TPB);
  hipLaunchKernelGGL(fps_kernel, grid, block, 0, stream, pts, out, slots);
}